// Round 10
// baseline (239.948 us; speedup 1.0000x reference)
//
#include <hip/hip_runtime.h>

// ScaledDotProductAttention fwd: out0 = attn output [2,16,2048,64] f32,
// out1 = attn weights [2,16,2048,2048] f32.
// Round 10 = round 9 (236us) + swapped-operand pass 2:
//  - pass 2 computes mfma(A=K, B=Q) (same frag addressing as pass-1 swapped,
//    validated): lane holds S[k=ct*16+g4*4+r][q=l15] -> 4 consecutive W cols
//    of ONE row -> one float4 NT store (was 16 scalar stores), 1 mask word
//    (was 4), scalar lpr (no lpn redistribution needed in pass 2).
// Pass 1 unchanged: in-register softmax via swapped QK^T + sigma-permuted V^T.

typedef __attribute__((ext_vector_type(4))) float f32x4;
typedef __attribute__((ext_vector_type(8))) short s16x8;
typedef __attribute__((ext_vector_type(4))) unsigned short u16x4;
typedef __attribute__((ext_vector_type(8))) unsigned short u16x8;
typedef __attribute__((ext_vector_type(4))) unsigned int u32x4;

#define S_LEN 2048
#define D_DIM 64
#define H_NUM 16
#define B_NUM 2
#define NT    32   // S/64 k-tiles
#define SW    32   // mask words per row (S/64)
#define QSCALE 0.18033688011112042f   // 0.125 * log2(e)

__device__ __forceinline__ int swz(int row, int colByte) {
  return row * 128 + (colByte ^ ((row & 7) << 4));
}

__device__ __forceinline__ unsigned short f2bf(float f) {  // RNE f32->bf16
  unsigned int x = __builtin_bit_cast(unsigned int, f);
  x = (x + 0x7FFFu + ((x >> 16) & 1u)) >> 16;
  return (unsigned short)x;
}

__device__ __forceinline__ unsigned cvt_pk_bf16(float lo, float hi) {
  unsigned r;
  asm("v_cvt_pk_bf16_f32 %0, %1, %2" : "=v"(r) : "v"(lo), "v"(hi));
  return r;
}

__device__ __forceinline__ f32x4 mfma16(f32x4 acc, s16x8 a, s16x8 b) {
  return __builtin_amdgcn_mfma_f32_16x16x32_bf16(a, b, acc, 0, 0, 0);
}

// ---------------- merged prep kernel ----------------
// blocks [0,1024): V transpose -> VT16[bh][d][kt*64 + t] with s-permutation
//   slot t0 holds s = ((t0>>5)&1)*32 + ((t0&7)>>2)*16 + ((t0>>3)&3)*4 + (t0&3)
// blocks [1024,2048): Q/K f32 -> bf16 (Q scaled by QSCALE)
// blocks [2048,3072): mask -> bit-pack

__global__ __launch_bounds__(256) void prep_kernel(
    const float* __restrict__ Q, const float* __restrict__ K,
    const float* __restrict__ V, const int* __restrict__ m,
    u16x4* __restrict__ Q16, u16x4* __restrict__ K16,
    unsigned short* __restrict__ VT, unsigned long long* __restrict__ bits)
{
  const int blk = blockIdx.x;
  const int tid = threadIdx.x;

  if (blk < 1024) {
    __shared__ unsigned short t[64][72];
    const int bh = blk >> 5;
    const int st = blk & 31;
    const float* src = V + ((size_t)bh * S_LEN + st * 64) * D_DIM;
    const int r0 = tid >> 4;
    const int c  = (tid & 15) * 4;
#pragma unroll
    for (int i = 0; i < 4; ++i) {
      const int r = r0 + i * 16;
      float4 v = *(const float4*)(src + r * D_DIM + c);
      t[c + 0][r] = f2bf(v.x); t[c + 1][r] = f2bf(v.y);
      t[c + 2][r] = f2bf(v.z); t[c + 3][r] = f2bf(v.w);
    }
    __syncthreads();
#pragma unroll
    for (int i = 0; i < 4; ++i) {
      const int idx = tid + i * 256;
      const int d  = idx >> 4;
      const int t0 = (idx & 15) * 4;                       // storage slot base
      const int sp = ((t0 >> 5) & 1) * 32 + ((t0 & 7) >> 2) * 16 + ((t0 >> 3) & 3) * 4;
      u16x4 o = *(const u16x4*)&t[d][sp];                  // 4 consecutive s
      *(u16x4*)(VT + ((size_t)bh * D_DIM + d) * S_LEN + st * 64 + t0) = o;
    }
  } else if (blk < 2048) {
    const int n4 = B_NUM * H_NUM * S_LEN * D_DIM / 4;  // 1048576
    const int step = 1024 * 256;
    for (int i = (blk - 1024) * 256 + tid; i < n4; i += step) {
      float4 q = ((const float4*)Q)[i];
      Q16[i] = u16x4{f2bf(q.x * QSCALE), f2bf(q.y * QSCALE),
                     f2bf(q.z * QSCALE), f2bf(q.w * QSCALE)};
      float4 k = ((const float4*)K)[i];
      K16[i] = u16x4{f2bf(k.x), f2bf(k.y), f2bf(k.z), f2bf(k.w)};
    }
  } else {
    const int total = B_NUM * S_LEN * S_LEN;   // 8388608
    const int step  = 1024 * 256;
    for (int i = (blk - 2048) * 256 + tid; i < total; i += step) {
      unsigned long long b = __ballot(m[i] != 0);
      if ((tid & 63) == 0) bits[i >> 6] = b;
    }
  }
}

// ---------------- fused main kernel ----------------

__global__ __launch_bounds__(256) void attn_fused_kernel(
    const unsigned short* __restrict__ Q16, const unsigned short* __restrict__ K16,
    const unsigned short* __restrict__ VT16, const unsigned long long* __restrict__ Mb,
    float* __restrict__ Op, float* __restrict__ Wp)
{
  const int tid  = threadIdx.x;
  const int lane = tid & 63;
  const int wv   = tid >> 6;
  const int l15  = lane & 15;
  const int g4   = lane >> 4;

  const int wg = blockIdx.x;                 // 1024 blocks
  const int lg = (wg & 7) * 128 + (wg >> 3); // bijective XCD swizzle
  const int qt = lg & 31;
  const int bh = lg >> 5;
  const int b  = bh >> 4;

  __shared__ __align__(16) char lds[32768];
  char* Kbuf = lds;                          // 2 x [64 k][64 d] bf16 swz
  char* Vbuf = lds + 16384;                  // 2 x [64 d][64 s-perm] bf16 swz

  const unsigned short* Qg16 = Q16 + ((size_t)bh * S_LEN + qt * 64 + wv * 16 + l15) * D_DIM + g4 * 8;
  const unsigned short* Kg16 = K16 + (size_t)bh * S_LEN * D_DIM;
  const unsigned short* Vg   = VT16 + (size_t)bh * D_DIM * S_LEN;
  float* Og = Op + ((size_t)bh * S_LEN + qt * 64) * D_DIM;
  float* Wg = Wp + ((size_t)bh * S_LEN + qt * 64) * S_LEN;
  const unsigned long long* Mg = Mb + ((size_t)b * S_LEN + qt * 64) * SW;

  const s16x8 qa0 = *(const s16x8*)Qg16;       // Q[q=wv*16+l15][d=g4*8..], scaled
  const s16x8 qa1 = *(const s16x8*)(Qg16 + 32);

  f32x4 oacc[4];
#pragma unroll
  for (int i = 0; i < 4; ++i) oacc[i] = f32x4{0.f, 0.f, 0.f, 0.f};
  float lps = 0.f;                             // partial rowsum for q = wv*16+l15

  // staging geometry: thread -> rows {sr, sr+32}, 16B slot ss
  const int sr  = tid >> 3;
  const int ss  = tid & 7;
  const int ssb = ss * 16;

  // ---- prologue: stage tile 0 into buffer 0 ----
  {
    u16x8 k0 = *(const u16x8*)(Kg16 + (size_t)sr * D_DIM + ss * 8);
    u16x8 k1 = *(const u16x8*)(Kg16 + (size_t)(sr + 32) * D_DIM + ss * 8);
    u16x8 v0 = *(const u16x8*)(Vg + (size_t)sr * S_LEN + ss * 8);
    u16x8 v1 = *(const u16x8*)(Vg + (size_t)(sr + 32) * S_LEN + ss * 8);
    *(u16x8*)(Kbuf + swz(sr, ssb))      = k0;
    *(u16x8*)(Kbuf + swz(sr + 32, ssb)) = k1;
    *(u16x8*)(Vbuf + swz(sr, ssb))      = v0;
    *(u16x8*)(Vbuf + swz(sr + 32, ssb)) = v1;
  }
  __syncthreads();

  // ================= PASS 1: rowsum + O accumulate =================
  int cur = 0;
  for (int kt = 0; kt < NT; ++kt) {
    const int ktn = (kt + 1 < NT) ? kt + 1 : kt;
    u16x8 kr0 = *(const u16x8*)(Kg16 + (size_t)(ktn * 64 + sr) * D_DIM + ss * 8);
    u16x8 kr1 = *(const u16x8*)(Kg16 + (size_t)(ktn * 64 + sr + 32) * D_DIM + ss * 8);
    u16x8 vr0 = *(const u16x8*)(Vg + (size_t)sr * S_LEN + ktn * 64 + ss * 8);
    u16x8 vr1 = *(const u16x8*)(Vg + (size_t)(sr + 32) * S_LEN + ktn * 64 + ss * 8);
    __builtin_amdgcn_sched_barrier(0);   // pin load issue above compute

    char* Kc = Kbuf + cur * 8192;
    char* Vc = Vbuf + cur * 8192;

    // mask word: q row = wv*16+l15, 64 k-bits of tile kt
    const unsigned long long mw = Mg[(wv * 16 + l15) * SW + kt];

    // SWAPPED QK^T: A=K, B=Q -> sacc[ct][r] = S[k=ct*16+g4*4+r][q=wv*16+l15]
    f32x4 sacc[4];
#pragma unroll
    for (int i = 0; i < 4; ++i) sacc[i] = f32x4{0.f, 0.f, 0.f, 0.f};
#pragma unroll
    for (int ct = 0; ct < 4; ++ct) {
      s16x8 b0 = *(const s16x8*)(Kc + swz(ct * 16 + l15, g4 * 16));
      s16x8 b1 = *(const s16x8*)(Kc + swz(ct * 16 + l15, g4 * 16 + 64));
      sacc[ct] = mfma16(sacc[ct], b0, qa0);
      sacc[ct] = mfma16(sacc[ct], b1, qa1);
    }

    // exp + mask + rowsum, all in-register; pack to PV A-frags via cvt_pk
    float ev[4][4];
#pragma unroll
    for (int ct = 0; ct < 4; ++ct) {
#pragma unroll
      for (int r = 0; r < 4; ++r) {
        float e = __builtin_amdgcn_exp2f(sacc[ct][r]);
        e = ((mw >> (ct * 16 + g4 * 4 + r)) & 1ull) ? e : 0.f;
        ev[ct][r] = e;
      }
      lps += (ev[ct][0] + ev[ct][1]) + (ev[ct][2] + ev[ct][3]);
    }
    const u32x4 a0 = {cvt_pk_bf16(ev[0][0], ev[0][1]), cvt_pk_bf16(ev[0][2], ev[0][3]),
                      cvt_pk_bf16(ev[1][0], ev[1][1]), cvt_pk_bf16(ev[1][2], ev[1][3])};
    const u32x4 a1 = {cvt_pk_bf16(ev[2][0], ev[2][1]), cvt_pk_bf16(ev[2][2], ev[2][3]),
                      cvt_pk_bf16(ev[3][0], ev[3][1]), cvt_pk_bf16(ev[3][2], ev[3][3])};
    const s16x8 pa0 = __builtin_bit_cast(s16x8, a0);  // P[q=l15][s=sigma(g4,j)]
    const s16x8 pa1 = __builtin_bit_cast(s16x8, a1);  // P[q=l15][s=32+sigma(g4,j)]

    // PV: A=P (in regs), B=V^T (s-permuted staging matches sigma)
#pragma unroll
    for (int ct = 0; ct < 4; ++ct) {
      s16x8 v0 = *(const s16x8*)(Vc + swz(ct * 16 + l15, g4 * 16));
      s16x8 v1 = *(const s16x8*)(Vc + swz(ct * 16 + l15, g4 * 16 + 64));
      oacc[ct] = mfma16(oacc[ct], pa0, v0);
      oacc[ct] = mfma16(oacc[ct], pa1, v1);
    }

    char* Kn = Kbuf + (cur ^ 1) * 8192;
    char* Vn = Vbuf + (cur ^ 1) * 8192;
    *(u16x8*)(Kn + swz(sr, ssb))      = kr0;
    *(u16x8*)(Kn + swz(sr + 32, ssb)) = kr1;
    *(u16x8*)(Vn + swz(sr, ssb))      = vr0;
    *(u16x8*)(Vn + swz(sr + 32, ssb)) = vr1;
    __syncthreads();
    cur ^= 1;
  }

  // rowsum: lanes sharing l15 (g4=0..3) hold disjoint k-ranges of q=wv*16+l15
  lps += __shfl_xor(lps, 16);
  lps += __shfl_xor(lps, 32);
  const float lpr = 1.0f / lps;               // 1/l for q = wv*16+l15

  // redistribute for O store: lane needs 1/l for q = wv*16 + g4*4 + r
  float lpn[4];
#pragma unroll
  for (int r = 0; r < 4; ++r) lpn[r] = __shfl(lpr, g4 * 4 + r);

  // O store: oacc[ct][r] = O[q=wv*16+g4*4+r][d=ct*16+l15]
#pragma unroll
  for (int ct = 0; ct < 4; ++ct)
#pragma unroll
    for (int r = 0; r < 4; ++r)
      Og[(size_t)(wv * 16 + g4 * 4 + r) * D_DIM + ct * 16 + l15] = oacc[ct][r] * lpn[r];

  __builtin_amdgcn_sched_barrier(0);

  // ===== PASS 2: swapped-operand weight stream =====
  // A=K (rows l15), B=Q -> lane holds S[k=ct*16+g4*4+r][q=wv*16+l15]:
  // 4 consecutive W columns of one row -> float4 NT store; 1 mask word; lpr.
  float* Wrow = Wg + (size_t)(wv * 16 + l15) * S_LEN;
  const unsigned long long* Mrow = Mg + (wv * 16 + l15) * SW;

  s16x8 kb0[4], kb1[4];
#pragma unroll
  for (int ct = 0; ct < 4; ++ct) {
    const unsigned short* kp = Kg16 + (size_t)(ct * 16 + l15) * D_DIM + g4 * 8;
    kb0[ct] = *(const s16x8*)kp;
    kb1[ct] = *(const s16x8*)(kp + 32);
  }

  for (int kt = 0; kt < NT; ++kt) {
    const int ktn = (kt < NT - 1) ? kt + 1 : kt;
    s16x8 nk0[4], nk1[4];
#pragma unroll
    for (int ct = 0; ct < 4; ++ct) {
      const unsigned short* kp = Kg16 + (size_t)(ktn * 64 + ct * 16 + l15) * D_DIM + g4 * 8;
      nk0[ct] = *(const s16x8*)kp;
      nk1[ct] = *(const s16x8*)(kp + 32);
    }

    const unsigned long long mw = Mrow[kt];

    f32x4 sacc[4];
#pragma unroll
    for (int i = 0; i < 4; ++i) sacc[i] = f32x4{0.f, 0.f, 0.f, 0.f};
#pragma unroll
    for (int ct = 0; ct < 4; ++ct) {
      sacc[ct] = mfma16(sacc[ct], kb0[ct], qa0);
      sacc[ct] = mfma16(sacc[ct], kb1[ct], qa1);
    }

#pragma unroll
    for (int ct = 0; ct < 4; ++ct) {
      f32x4 w;
#pragma unroll
      for (int r = 0; r < 4; ++r) {
        float e = __builtin_amdgcn_exp2f(sacc[ct][r]);
        w[r] = ((mw >> (ct * 16 + g4 * 4 + r)) & 1ull) ? e * lpr : 0.f;
      }
      __builtin_nontemporal_store(w,
          (f32x4*)(Wrow + (size_t)kt * 64 + ct * 16 + g4 * 4));
    }
#pragma unroll
    for (int ct = 0; ct < 4; ++ct) { kb0[ct] = nk0[ct]; kb1[ct] = nk1[ct]; }
  }
}

// ---------------- fallback (fp32 inputs, LDS-staged, int mask) ----------------

__global__ __launch_bounds__(256) void attn_fwd_kernel(
    const float* __restrict__ Qp, const float* __restrict__ Kp, const float* __restrict__ Vp,
    const int* __restrict__ Mi, float* __restrict__ Op, float* __restrict__ Wp)
{
  const int tid  = threadIdx.x;
  const int lane = tid & 63;
  const int wv   = tid >> 6;
  const int l15  = lane & 15;
  const int g4   = lane >> 4;

  const int wg = blockIdx.x;
  const int lg = (wg & 7) * 128 + (wg >> 3);
  const int qt = lg & 31;
  const int bh = lg >> 5;
  const int b  = bh >> 4;

  __shared__ __align__(16) char lds[32768];
  char* Qs  = lds;
  char* Ks  = lds + 8192;
  char* VTs = lds + 16384;
  char* Ps  = lds + 24576 + (wv << 11);

  const float* Qg = Qp + ((size_t)bh * S_LEN + qt * 64) * D_DIM;
  const float* Kg = Kp + (size_t)bh * S_LEN * D_DIM;
  const float* Vg = Vp + (size_t)bh * S_LEN * D_DIM;
  float* Og = Op + ((size_t)bh * S_LEN + qt * 64) * D_DIM;
  float* Wg = Wp + ((size_t)bh * S_LEN + qt * 64) * S_LEN;
  const int* Mig = Mi + ((size_t)b * S_LEN + qt * 64) * S_LEN;

  {
    const int r0 = tid >> 4;
    const int c  = (tid & 15) * 4;
#pragma unroll
    for (int i = 0; i < 4; ++i) {
      const int r = r0 + i * 16;
      float4 v = *(const float4*)(Qg + r * D_DIM + c);
      ushort4 p; p.x = f2bf(v.x); p.y = f2bf(v.y); p.z = f2bf(v.z); p.w = f2bf(v.w);
      *(ushort4*)(Qs + swz(r, c * 2)) = p;
    }
  }
  __syncthreads();
  const s16x8 qa0 = *(const s16x8*)(Qs + swz(wv * 16 + l15, g4 * 16));
  const s16x8 qa1 = *(const s16x8*)(Qs + swz(wv * 16 + l15, g4 * 16 + 64));

  f32x4 oacc[4];
#pragma unroll
  for (int i = 0; i < 4; ++i) oacc[i] = f32x4{0.f, 0.f, 0.f, 0.f};
  float lp[4] = {0.f, 0.f, 0.f, 0.f};

  const int qrow = wv * 16 + g4 * 4;

  for (int kt = 0; kt < NT; ++kt) {
    __syncthreads();
    {
      const int r0 = tid >> 4;
      const int c  = (tid & 15) * 4;
      const float* Kt = Kg + kt * 64 * D_DIM;
#pragma unroll
      for (int i = 0; i < 4; ++i) {
        const int r = r0 + i * 16;
        float4 v = *(const float4*)(Kt + r * D_DIM + c);
        ushort4 p; p.x = f2bf(v.x); p.y = f2bf(v.y); p.z = f2bf(v.z); p.w = f2bf(v.w);
        *(ushort4*)(Ks + swz(r, c * 2)) = p;
      }
      const float* Vt = Vg + kt * 64 * D_DIM;
#pragma unroll
      for (int i = 0; i < 2; ++i) {
        const int rr = (tid >> 4) * 2 + i * 32;
        float4 a  = *(const float4*)(Vt + rr * D_DIM + c);
        float4 bq = *(const float4*)(Vt + (rr + 1) * D_DIM + c);
        const float av[4] = {a.x, a.y, a.z, a.w};
        const float bv[4] = {bq.x, bq.y, bq.z, bq.w};
#pragma unroll
        for (int j = 0; j < 4; ++j) {
          unsigned pk = (unsigned)f2bf(av[j]) | ((unsigned)f2bf(bv[j]) << 16);
          *(unsigned*)(VTs + swz(c + j, rr * 2)) = pk;
        }
      }
    }
    __syncthreads();

    f32x4 sacc[4];
#pragma unroll
    for (int i = 0; i < 4; ++i) sacc[i] = f32x4{0.f, 0.f, 0.f, 0.f};
#pragma unroll
    for (int ct = 0; ct < 4; ++ct) {
      s16x8 b0 = *(const s16x8*)(Ks + swz(ct * 16 + l15, g4 * 16));
      s16x8 b1 = *(const s16x8*)(Ks + swz(ct * 16 + l15, g4 * 16 + 64));
      sacc[ct] = mfma16(sacc[ct], qa0, b0);
      sacc[ct] = mfma16(sacc[ct], qa1, b1);
    }

#pragma unroll
    for (int ct = 0; ct < 4; ++ct) {
#pragma unroll
      for (int r = 0; r < 4; ++r) {
        float e = __expf(sacc[ct][r] * 0.125f);
        bool keep = Mig[(size_t)(qrow + r) * S_LEN + kt * 64 + ct * 16 + l15] != 0;
        e = keep ? e : 0.f;
        lp[r] += e;
        *(unsigned short*)(Ps + swz(g4 * 4 + r, (ct * 16 + l15) * 2)) = f2bf(e);
      }
    }
    asm volatile("s_waitcnt lgkmcnt(0)" ::: "memory");
    __builtin_amdgcn_sched_barrier(0);

    const s16x8 pa0 = *(const s16x8*)(Ps + swz(l15, g4 * 16));
    const s16x8 pa1 = *(const s16x8*)(Ps + swz(l15, g4 * 16 + 64));
#pragma unroll
    for (int ct = 0; ct < 4; ++ct) {
      s16x8 v0 = *(const s16x8*)(VTs + swz(ct * 16 + l15, g4 * 16));
      s16x8 v1 = *(const s16x8*)(VTs + swz(ct * 16 + l15, g4 * 16 + 64));
      oacc[ct] = mfma16(oacc[ct], pa0, v0);
      oacc[ct] = mfma16(oacc[ct], pa1, v1);
    }
  }

#pragma unroll
  for (int r = 0; r < 4; ++r) {
    float v = lp[r];
    v += __shfl_xor(v, 1);
    v += __shfl_xor(v, 2);
    v += __shfl_xor(v, 4);
    v += __shfl_xor(v, 8);
    lp[r] = 1.0f / v;
  }

#pragma unroll
  for (int ct = 0; ct < 4; ++ct)
#pragma unroll
    for (int r = 0; r < 4; ++r)
      Og[(size_t)(qrow + r) * D_DIM + ct * 16 + l15] = oacc[ct][r] * lp[r];

  for (int kt = 0; kt < NT; ++kt) {
    __syncthreads();
    {
      const int r0 = tid >> 4;
      const int c  = (tid & 15) * 4;
      const float* Kt = Kg + kt * 64 * D_DIM;
#pragma unroll
      for (int i = 0; i < 4; ++i) {
        const int r = r0 + i * 16;
        float4 v = *(const float4*)(Kt + r * D_DIM + c);
        ushort4 p; p.x = f2bf(v.x); p.y = f2bf(v.y); p.z = f2bf(v.z); p.w = f2bf(v.w);
        *(ushort4*)(Ks + swz(r, c * 2)) = p;
      }
    }
    __syncthreads();

    f32x4 sacc[4];
#pragma unroll
    for (int i = 0; i < 4; ++i) sacc[i] = f32x4{0.f, 0.f, 0.f, 0.f};
#pragma unroll
    for (int ct = 0; ct < 4; ++ct) {
      s16x8 b0 = *(const s16x8*)(Ks + swz(ct * 16 + l15, g4 * 16));
      s16x8 b1 = *(const s16x8*)(Ks + swz(ct * 16 + l15, g4 * 16 + 64));
      sacc[ct] = mfma16(sacc[ct], qa0, b0);
      sacc[ct] = mfma16(sacc[ct], qa1, b1);
    }

#pragma unroll
    for (int ct = 0; ct < 4; ++ct) {
#pragma unroll
      for (int r = 0; r < 4; ++r) {
        float e = __expf(sacc[ct][r] * 0.125f);
        bool keep = Mig[(size_t)(qrow + r) * S_LEN + kt * 64 + ct * 16 + l15] != 0;
        e = keep ? e : 0.f;
        __builtin_nontemporal_store(e * lp[r],
            Wg + (size_t)(qrow + r) * S_LEN + kt * 64 + ct * 16 + l15);
      }
    }
  }
}

extern "C" void kernel_launch(void* const* d_in, const int* in_sizes, int n_in,
                              void* d_out, int out_size, void* d_ws, size_t ws_size,
                              hipStream_t stream) {
  (void)in_sizes; (void)n_in; (void)out_size;
  const float* Q   = (const float*)d_in[0];
  const float* K   = (const float*)d_in[1];
  const float* V   = (const float*)d_in[2];
  const int* mask  = (const int*)d_in[3];
  float* Out = (float*)d_out;
  float* W   = Out + (size_t)B_NUM * H_NUM * S_LEN * D_DIM;

  const size_t bits_bytes = (size_t)(B_NUM * S_LEN * S_LEN / 64) * 8;      // 1 MiB
  const size_t t16_bytes  = (size_t)B_NUM * H_NUM * S_LEN * D_DIM * 2;     // 8 MiB
  unsigned long long* bits = (unsigned long long*)d_ws;

  if (ws_size >= bits_bytes + 3 * t16_bytes) {
    unsigned short* Q16 = (unsigned short*)((char*)d_ws + bits_bytes);
    unsigned short* K16 = Q16 + t16_bytes / 2;
    unsigned short* VT  = K16 + t16_bytes / 2;
    prep_kernel<<<3072, 256, 0, stream>>>(Q, K, V, mask,
                                          (u16x4*)Q16, (u16x4*)K16, VT, bits);
    attn_fused_kernel<<<1024, 256, 0, stream>>>(Q16, K16, VT, bits, Out, W);
  } else {
    attn_fwd_kernel<<<1024, 256, 0, stream>>>(Q, K, V, mask, Out, W);
  }
}

// Round 11
// 230.110 us; speedup vs baseline: 1.0428x; 1.0428x over previous
//
#include <hip/hip_runtime.h>

// ScaledDotProductAttention fwd: out0 = attn output [2,16,2048,64] f32,
// out1 = attn weights [2,16,2048,2048] f32.
// Round 11 = round 9/10 per-wave bodies (validated), new geometry:
//  512-thread blocks (8 waves), each block = TWO q-tiles of one bh sharing
//  one K/V staging stream -> per-thread staging halved, per-kt barrier cost
//  amortized over 2x compute. Grid 512, bijective XCD swizzle.
//  __launch_bounds__(512,4) caps VGPR at 128 (>=4 waves/SIMD).

typedef __attribute__((ext_vector_type(4))) float f32x4;
typedef __attribute__((ext_vector_type(8))) short s16x8;
typedef __attribute__((ext_vector_type(4))) unsigned short u16x4;
typedef __attribute__((ext_vector_type(8))) unsigned short u16x8;
typedef __attribute__((ext_vector_type(4))) unsigned int u32x4;

#define S_LEN 2048
#define D_DIM 64
#define H_NUM 16
#define B_NUM 2
#define NT    32   // S/64 k-tiles
#define SW    32   // mask words per row (S/64)
#define QSCALE 0.18033688011112042f   // 0.125 * log2(e)

__device__ __forceinline__ int swz(int row, int colByte) {
  return row * 128 + (colByte ^ ((row & 7) << 4));
}

__device__ __forceinline__ unsigned short f2bf(float f) {  // RNE f32->bf16
  unsigned int x = __builtin_bit_cast(unsigned int, f);
  x = (x + 0x7FFFu + ((x >> 16) & 1u)) >> 16;
  return (unsigned short)x;
}

__device__ __forceinline__ unsigned cvt_pk_bf16(float lo, float hi) {
  unsigned r;
  asm("v_cvt_pk_bf16_f32 %0, %1, %2" : "=v"(r) : "v"(lo), "v"(hi));
  return r;
}

__device__ __forceinline__ f32x4 mfma16(f32x4 acc, s16x8 a, s16x8 b) {
  return __builtin_amdgcn_mfma_f32_16x16x32_bf16(a, b, acc, 0, 0, 0);
}

// ---------------- merged prep kernel ----------------
// blocks [0,1024): V transpose -> VT16[bh][d][kt*64 + t] with s-permutation
//   slot t0 holds s = ((t0>>5)&1)*32 + ((t0&7)>>2)*16 + ((t0>>3)&3)*4 + (t0&3)
// blocks [1024,2048): Q/K f32 -> bf16 (Q scaled by QSCALE)
// blocks [2048,3072): mask -> bit-pack

__global__ __launch_bounds__(256) void prep_kernel(
    const float* __restrict__ Q, const float* __restrict__ K,
    const float* __restrict__ V, const int* __restrict__ m,
    u16x4* __restrict__ Q16, u16x4* __restrict__ K16,
    unsigned short* __restrict__ VT, unsigned long long* __restrict__ bits)
{
  const int blk = blockIdx.x;
  const int tid = threadIdx.x;

  if (blk < 1024) {
    __shared__ unsigned short t[64][72];
    const int bh = blk >> 5;
    const int st = blk & 31;
    const float* src = V + ((size_t)bh * S_LEN + st * 64) * D_DIM;
    const int r0 = tid >> 4;
    const int c  = (tid & 15) * 4;
#pragma unroll
    for (int i = 0; i < 4; ++i) {
      const int r = r0 + i * 16;
      float4 v = *(const float4*)(src + r * D_DIM + c);
      t[c + 0][r] = f2bf(v.x); t[c + 1][r] = f2bf(v.y);
      t[c + 2][r] = f2bf(v.z); t[c + 3][r] = f2bf(v.w);
    }
    __syncthreads();
#pragma unroll
    for (int i = 0; i < 4; ++i) {
      const int idx = tid + i * 256;
      const int d  = idx >> 4;
      const int t0 = (idx & 15) * 4;                       // storage slot base
      const int sp = ((t0 >> 5) & 1) * 32 + ((t0 & 7) >> 2) * 16 + ((t0 >> 3) & 3) * 4;
      u16x4 o = *(const u16x4*)&t[d][sp];                  // 4 consecutive s
      *(u16x4*)(VT + ((size_t)bh * D_DIM + d) * S_LEN + st * 64 + t0) = o;
    }
  } else if (blk < 2048) {
    const int n4 = B_NUM * H_NUM * S_LEN * D_DIM / 4;  // 1048576
    const int step = 1024 * 256;
    for (int i = (blk - 1024) * 256 + tid; i < n4; i += step) {
      float4 q = ((const float4*)Q)[i];
      Q16[i] = u16x4{f2bf(q.x * QSCALE), f2bf(q.y * QSCALE),
                     f2bf(q.z * QSCALE), f2bf(q.w * QSCALE)};
      float4 k = ((const float4*)K)[i];
      K16[i] = u16x4{f2bf(k.x), f2bf(k.y), f2bf(k.z), f2bf(k.w)};
    }
  } else {
    const int total = B_NUM * S_LEN * S_LEN;   // 8388608
    const int step  = 1024 * 256;
    for (int i = (blk - 2048) * 256 + tid; i < total; i += step) {
      unsigned long long b = __ballot(m[i] != 0);
      if ((tid & 63) == 0) bits[i >> 6] = b;
    }
  }
}

// ---------------- fused main kernel (512 threads, 2 q-tiles/block) ----------------

__global__ __launch_bounds__(512, 4) void attn_fused_kernel(
    const unsigned short* __restrict__ Q16, const unsigned short* __restrict__ K16,
    const unsigned short* __restrict__ VT16, const unsigned long long* __restrict__ Mb,
    float* __restrict__ Op, float* __restrict__ Wp)
{
  const int tid  = threadIdx.x;
  const int lane = tid & 63;
  const int wv   = tid >> 6;     // 0..7
  const int l15  = lane & 15;
  const int g4   = lane >> 4;
  const int wt   = wv & 3;       // wave-within-tile

  const int wg = blockIdx.x;                 // 512 blocks
  const int lg = (wg & 7) * 64 + (wg >> 3);  // bijective XCD swizzle (512%8==0)
  const int tp = lg & 15;                    // tile pair
  const int bh = lg >> 4;                    // b*H + h
  const int b  = bh >> 4;
  const int qt = tp * 2 + (wv >> 2);         // this wave's q-tile

  __shared__ __align__(16) char lds[32768];
  char* Kbuf = lds;                          // 2 x [64 k][64 d] bf16 swz
  char* Vbuf = lds + 16384;                  // 2 x [64 d][64 s-perm] bf16 swz

  const unsigned short* Qg16 = Q16 + ((size_t)bh * S_LEN + qt * 64 + wt * 16 + l15) * D_DIM + g4 * 8;
  const unsigned short* Kg16 = K16 + (size_t)bh * S_LEN * D_DIM;
  const unsigned short* Vg   = VT16 + (size_t)bh * D_DIM * S_LEN;
  float* Og = Op + ((size_t)bh * S_LEN + qt * 64) * D_DIM;
  float* Wg = Wp + ((size_t)bh * S_LEN + qt * 64) * S_LEN;
  const unsigned long long* Mg = Mb + ((size_t)b * S_LEN + qt * 64) * SW;

  const s16x8 qa0 = *(const s16x8*)Qg16;       // Q[q=qt*64+wt*16+l15][d], scaled
  const s16x8 qa1 = *(const s16x8*)(Qg16 + 32);

  f32x4 oacc[4];
#pragma unroll
  for (int i = 0; i < 4; ++i) oacc[i] = f32x4{0.f, 0.f, 0.f, 0.f};
  float lps = 0.f;                             // partial rowsum for q = ..+l15

  // staging geometry: 512 threads -> one K row-slot + one V row-slot each
  const int sr  = tid >> 3;   // 0..63
  const int ss  = tid & 7;    // 16B slot
  const int ssb = ss * 16;

  // ---- prologue: stage tile 0 into buffer 0 ----
  {
    u16x8 k0 = *(const u16x8*)(Kg16 + (size_t)sr * D_DIM + ss * 8);
    u16x8 v0 = *(const u16x8*)(Vg + (size_t)sr * S_LEN + ss * 8);
    *(u16x8*)(Kbuf + swz(sr, ssb)) = k0;
    *(u16x8*)(Vbuf + swz(sr, ssb)) = v0;
  }
  __syncthreads();

  // ================= PASS 1: rowsum + O accumulate =================
  int cur = 0;
  for (int kt = 0; kt < NT; ++kt) {
    const int ktn = (kt + 1 < NT) ? kt + 1 : kt;
    u16x8 kr = *(const u16x8*)(Kg16 + (size_t)(ktn * 64 + sr) * D_DIM + ss * 8);
    u16x8 vr = *(const u16x8*)(Vg + (size_t)sr * S_LEN + ktn * 64 + ss * 8);
    __builtin_amdgcn_sched_barrier(0);   // pin load issue above compute

    char* Kc = Kbuf + cur * 8192;
    char* Vc = Vbuf + cur * 8192;

    // mask word: q row = wt*16+l15 (within tile), 64 k-bits of tile kt
    const unsigned long long mw = Mg[(wt * 16 + l15) * SW + kt];

    // SWAPPED QK^T: A=K, B=Q -> sacc[ct][r] = S[k=ct*16+g4*4+r][q]
    f32x4 sacc[4];
#pragma unroll
    for (int i = 0; i < 4; ++i) sacc[i] = f32x4{0.f, 0.f, 0.f, 0.f};
#pragma unroll
    for (int ct = 0; ct < 4; ++ct) {
      s16x8 b0 = *(const s16x8*)(Kc + swz(ct * 16 + l15, g4 * 16));
      s16x8 b1 = *(const s16x8*)(Kc + swz(ct * 16 + l15, g4 * 16 + 64));
      sacc[ct] = mfma16(sacc[ct], b0, qa0);
      sacc[ct] = mfma16(sacc[ct], b1, qa1);
    }

    // exp + mask + rowsum in-register; pack to PV A-frags via cvt_pk
    unsigned pw[8];
#pragma unroll
    for (int ct = 0; ct < 4; ++ct) {
      float e0 = __builtin_amdgcn_exp2f(sacc[ct][0]);
      float e1 = __builtin_amdgcn_exp2f(sacc[ct][1]);
      float e2 = __builtin_amdgcn_exp2f(sacc[ct][2]);
      float e3 = __builtin_amdgcn_exp2f(sacc[ct][3]);
      e0 = ((mw >> (ct * 16 + g4 * 4 + 0)) & 1ull) ? e0 : 0.f;
      e1 = ((mw >> (ct * 16 + g4 * 4 + 1)) & 1ull) ? e1 : 0.f;
      e2 = ((mw >> (ct * 16 + g4 * 4 + 2)) & 1ull) ? e2 : 0.f;
      e3 = ((mw >> (ct * 16 + g4 * 4 + 3)) & 1ull) ? e3 : 0.f;
      lps += (e0 + e1) + (e2 + e3);
      pw[2 * ct]     = cvt_pk_bf16(e0, e1);
      pw[2 * ct + 1] = cvt_pk_bf16(e2, e3);
    }
    const s16x8 pa0 = __builtin_bit_cast(s16x8, u32x4{pw[0], pw[1], pw[2], pw[3]});
    const s16x8 pa1 = __builtin_bit_cast(s16x8, u32x4{pw[4], pw[5], pw[6], pw[7]});

    // PV: A=P (in regs), B=V^T (s-permuted staging matches sigma)
#pragma unroll
    for (int ct = 0; ct < 4; ++ct) {
      s16x8 v0 = *(const s16x8*)(Vc + swz(ct * 16 + l15, g4 * 16));
      s16x8 v1 = *(const s16x8*)(Vc + swz(ct * 16 + l15, g4 * 16 + 64));
      oacc[ct] = mfma16(oacc[ct], pa0, v0);
      oacc[ct] = mfma16(oacc[ct], pa1, v1);
    }

    char* Kn = Kbuf + (cur ^ 1) * 8192;
    char* Vn = Vbuf + (cur ^ 1) * 8192;
    *(u16x8*)(Kn + swz(sr, ssb)) = kr;
    *(u16x8*)(Vn + swz(sr, ssb)) = vr;
    __syncthreads();
    cur ^= 1;
  }

  // rowsum: lanes sharing l15 (g4=0..3) hold disjoint k-ranges of this q
  lps += __shfl_xor(lps, 16);
  lps += __shfl_xor(lps, 32);
  const float lpr = 1.0f / lps;               // 1/l for q = qt*64+wt*16+l15

  // redistribute for O store: lane needs 1/l for q row wt*16 + g4*4 + r
  float lpn[4];
#pragma unroll
  for (int r = 0; r < 4; ++r) lpn[r] = __shfl(lpr, g4 * 4 + r);

  // O store: oacc[ct][r] = O[q=wt*16+g4*4+r][d=ct*16+l15]
#pragma unroll
  for (int ct = 0; ct < 4; ++ct)
#pragma unroll
    for (int r = 0; r < 4; ++r)
      Og[(size_t)(wt * 16 + g4 * 4 + r) * D_DIM + ct * 16 + l15] = oacc[ct][r] * lpn[r];

  __builtin_amdgcn_sched_barrier(0);

  // ===== PASS 2: swapped-operand weight stream (validated round 10) =====
  float* Wrow = Wg + (size_t)(wt * 16 + l15) * S_LEN;
  const unsigned long long* Mrow = Mg + (wt * 16 + l15) * SW;

  s16x8 kb0[4], kb1[4];
#pragma unroll
  for (int ct = 0; ct < 4; ++ct) {
    const unsigned short* kp = Kg16 + (size_t)(ct * 16 + l15) * D_DIM + g4 * 8;
    kb0[ct] = *(const s16x8*)kp;
    kb1[ct] = *(const s16x8*)(kp + 32);
  }

  for (int kt = 0; kt < NT; ++kt) {
    const int ktn = (kt < NT - 1) ? kt + 1 : kt;
    s16x8 nk0[4], nk1[4];
#pragma unroll
    for (int ct = 0; ct < 4; ++ct) {
      const unsigned short* kp = Kg16 + (size_t)(ktn * 64 + ct * 16 + l15) * D_DIM + g4 * 8;
      nk0[ct] = *(const s16x8*)kp;
      nk1[ct] = *(const s16x8*)(kp + 32);
    }

    const unsigned long long mw = Mrow[kt];

    f32x4 sacc[4];
#pragma unroll
    for (int i = 0; i < 4; ++i) sacc[i] = f32x4{0.f, 0.f, 0.f, 0.f};
#pragma unroll
    for (int ct = 0; ct < 4; ++ct) {
      sacc[ct] = mfma16(sacc[ct], kb0[ct], qa0);
      sacc[ct] = mfma16(sacc[ct], kb1[ct], qa1);
    }

#pragma unroll
    for (int ct = 0; ct < 4; ++ct) {
      f32x4 w;
#pragma unroll
      for (int r = 0; r < 4; ++r) {
        float e = __builtin_amdgcn_exp2f(sacc[ct][r]);
        w[r] = ((mw >> (ct * 16 + g4 * 4 + r)) & 1ull) ? e * lpr : 0.f;
      }
      __builtin_nontemporal_store(w,
          (f32x4*)(Wrow + (size_t)kt * 64 + ct * 16 + g4 * 4));
    }
#pragma unroll
    for (int ct = 0; ct < 4; ++ct) { kb0[ct] = nk0[ct]; kb1[ct] = nk1[ct]; }
  }
}

// ---------------- fallback (fp32 inputs, LDS-staged, int mask) ----------------

__global__ __launch_bounds__(256) void attn_fwd_kernel(
    const float* __restrict__ Qp, const float* __restrict__ Kp, const float* __restrict__ Vp,
    const int* __restrict__ Mi, float* __restrict__ Op, float* __restrict__ Wp)
{
  const int tid  = threadIdx.x;
  const int lane = tid & 63;
  const int wv   = tid >> 6;
  const int l15  = lane & 15;
  const int g4   = lane >> 4;

  const int wg = blockIdx.x;
  const int lg = (wg & 7) * 128 + (wg >> 3);
  const int qt = lg & 31;
  const int bh = lg >> 5;
  const int b  = bh >> 4;

  __shared__ __align__(16) char lds[32768];
  char* Qs  = lds;
  char* Ks  = lds + 8192;
  char* VTs = lds + 16384;
  char* Ps  = lds + 24576 + (wv << 11);

  const float* Qg = Qp + ((size_t)bh * S_LEN + qt * 64) * D_DIM;
  const float* Kg = Kp + (size_t)bh * S_LEN * D_DIM;
  const float* Vg = Vp + (size_t)bh * S_LEN * D_DIM;
  float* Og = Op + ((size_t)bh * S_LEN + qt * 64) * D_DIM;
  float* Wg = Wp + ((size_t)bh * S_LEN + qt * 64) * S_LEN;
  const int* Mig = Mi + ((size_t)b * S_LEN + qt * 64) * S_LEN;

  {
    const int r0 = tid >> 4;
    const int c  = (tid & 15) * 4;
#pragma unroll
    for (int i = 0; i < 4; ++i) {
      const int r = r0 + i * 16;
      float4 v = *(const float4*)(Qg + r * D_DIM + c);
      ushort4 p; p.x = f2bf(v.x); p.y = f2bf(v.y); p.z = f2bf(v.z); p.w = f2bf(v.w);
      *(ushort4*)(Qs + swz(r, c * 2)) = p;
    }
  }
  __syncthreads();
  const s16x8 qa0 = *(const s16x8*)(Qs + swz(wv * 16 + l15, g4 * 16));
  const s16x8 qa1 = *(const s16x8*)(Qs + swz(wv * 16 + l15, g4 * 16 + 64));

  f32x4 oacc[4];
#pragma unroll
  for (int i = 0; i < 4; ++i) oacc[i] = f32x4{0.f, 0.f, 0.f, 0.f};
  float lp[4] = {0.f, 0.f, 0.f, 0.f};

  const int qrow = wv * 16 + g4 * 4;

  for (int kt = 0; kt < NT; ++kt) {
    __syncthreads();
    {
      const int r0 = tid >> 4;
      const int c  = (tid & 15) * 4;
      const float* Kt = Kg + kt * 64 * D_DIM;
#pragma unroll
      for (int i = 0; i < 4; ++i) {
        const int r = r0 + i * 16;
        float4 v = *(const float4*)(Kt + r * D_DIM + c);
        ushort4 p; p.x = f2bf(v.x); p.y = f2bf(v.y); p.z = f2bf(v.z); p.w = f2bf(v.w);
        *(ushort4*)(Ks + swz(r, c * 2)) = p;
      }
      const float* Vt = Vg + kt * 64 * D_DIM;
#pragma unroll
      for (int i = 0; i < 2; ++i) {
        const int rr = (tid >> 4) * 2 + i * 32;
        float4 a  = *(const float4*)(Vt + rr * D_DIM + c);
        float4 bq = *(const float4*)(Vt + (rr + 1) * D_DIM + c);
        const float av[4] = {a.x, a.y, a.z, a.w};
        const float bv[4] = {bq.x, bq.y, bq.z, bq.w};
#pragma unroll
        for (int j = 0; j < 4; ++j) {
          unsigned pk = (unsigned)f2bf(av[j]) | ((unsigned)f2bf(bv[j]) << 16);
          *(unsigned*)(VTs + swz(c + j, rr * 2)) = pk;
        }
      }
    }
    __syncthreads();

    f32x4 sacc[4];
#pragma unroll
    for (int i = 0; i < 4; ++i) sacc[i] = f32x4{0.f, 0.f, 0.f, 0.f};
#pragma unroll
    for (int ct = 0; ct < 4; ++ct) {
      s16x8 b0 = *(const s16x8*)(Ks + swz(ct * 16 + l15, g4 * 16));
      s16x8 b1 = *(const s16x8*)(Ks + swz(ct * 16 + l15, g4 * 16 + 64));
      sacc[ct] = mfma16(sacc[ct], qa0, b0);
      sacc[ct] = mfma16(sacc[ct], qa1, b1);
    }

#pragma unroll
    for (int ct = 0; ct < 4; ++ct) {
#pragma unroll
      for (int r = 0; r < 4; ++r) {
        float e = __expf(sacc[ct][r] * 0.125f);
        bool keep = Mig[(size_t)(qrow + r) * S_LEN + kt * 64 + ct * 16 + l15] != 0;
        e = keep ? e : 0.f;
        lp[r] += e;
        *(unsigned short*)(Ps + swz(g4 * 4 + r, (ct * 16 + l15) * 2)) = f2bf(e);
      }
    }
    asm volatile("s_waitcnt lgkmcnt(0)" ::: "memory");
    __builtin_amdgcn_sched_barrier(0);

    const s16x8 pa0 = *(const s16x8*)(Ps + swz(l15, g4 * 16));
    const s16x8 pa1 = *(const s16x8*)(Ps + swz(l15, g4 * 16 + 64));
#pragma unroll
    for (int ct = 0; ct < 4; ++ct) {
      s16x8 v0 = *(const s16x8*)(VTs + swz(ct * 16 + l15, g4 * 16));
      s16x8 v1 = *(const s16x8*)(VTs + swz(ct * 16 + l15, g4 * 16 + 64));
      oacc[ct] = mfma16(oacc[ct], pa0, v0);
      oacc[ct] = mfma16(oacc[ct], pa1, v1);
    }
  }

#pragma unroll
  for (int r = 0; r < 4; ++r) {
    float v = lp[r];
    v += __shfl_xor(v, 1);
    v += __shfl_xor(v, 2);
    v += __shfl_xor(v, 4);
    v += __shfl_xor(v, 8);
    lp[r] = 1.0f / v;
  }

#pragma unroll
  for (int ct = 0; ct < 4; ++ct)
#pragma unroll
    for (int r = 0; r < 4; ++r)
      Og[(size_t)(qrow + r) * D_DIM + ct * 16 + l15] = oacc[ct][r] * lp[r];

  for (int kt = 0; kt < NT; ++kt) {
    __syncthreads();
    {
      const int r0 = tid >> 4;
      const int c  = (tid & 15) * 4;
      const float* Kt = Kg + kt * 64 * D_DIM;
#pragma unroll
      for (int i = 0; i < 4; ++i) {
        const int r = r0 + i * 16;
        float4 v = *(const float4*)(Kt + r * D_DIM + c);
        ushort4 p; p.x = f2bf(v.x); p.y = f2bf(v.y); p.z = f2bf(v.z); p.w = f2bf(v.w);
        *(ushort4*)(Ks + swz(r, c * 2)) = p;
      }
    }
    __syncthreads();

    f32x4 sacc[4];
#pragma unroll
    for (int i = 0; i < 4; ++i) sacc[i] = f32x4{0.f, 0.f, 0.f, 0.f};
#pragma unroll
    for (int ct = 0; ct < 4; ++ct) {
      s16x8 b0 = *(const s16x8*)(Ks + swz(ct * 16 + l15, g4 * 16));
      s16x8 b1 = *(const s16x8*)(Ks + swz(ct * 16 + l15, g4 * 16 + 64));
      sacc[ct] = mfma16(sacc[ct], qa0, b0);
      sacc[ct] = mfma16(sacc[ct], qa1, b1);
    }

#pragma unroll
    for (int ct = 0; ct < 4; ++ct) {
#pragma unroll
      for (int r = 0; r < 4; ++r) {
        float e = __expf(sacc[ct][r] * 0.125f);
        bool keep = Mig[(size_t)(qrow + r) * S_LEN + kt * 64 + ct * 16 + l15] != 0;
        e = keep ? e : 0.f;
        __builtin_nontemporal_store(e * lp[r],
            Wg + (size_t)(qrow + r) * S_LEN + kt * 64 + ct * 16 + l15);
      }
    }
  }
}

extern "C" void kernel_launch(void* const* d_in, const int* in_sizes, int n_in,
                              void* d_out, int out_size, void* d_ws, size_t ws_size,
                              hipStream_t stream) {
  (void)in_sizes; (void)n_in; (void)out_size;
  const float* Q   = (const float*)d_in[0];
  const float* K   = (const float*)d_in[1];
  const float* V   = (const float*)d_in[2];
  const int* mask  = (const int*)d_in[3];
  float* Out = (float*)d_out;
  float* W   = Out + (size_t)B_NUM * H_NUM * S_LEN * D_DIM;

  const size_t bits_bytes = (size_t)(B_NUM * S_LEN * S_LEN / 64) * 8;      // 1 MiB
  const size_t t16_bytes  = (size_t)B_NUM * H_NUM * S_LEN * D_DIM * 2;     // 8 MiB
  unsigned long long* bits = (unsigned long long*)d_ws;

  if (ws_size >= bits_bytes + 3 * t16_bytes) {
    unsigned short* Q16 = (unsigned short*)((char*)d_ws + bits_bytes);
    unsigned short* K16 = Q16 + t16_bytes / 2;
    unsigned short* VT  = K16 + t16_bytes / 2;
    prep_kernel<<<3072, 256, 0, stream>>>(Q, K, V, mask,
                                          (u16x4*)Q16, (u16x4*)K16, VT, bits);
    attn_fused_kernel<<<512, 512, 0, stream>>>(Q16, K16, VT, bits, Out, W);
  } else {
    attn_fwd_kernel<<<1024, 256, 0, stream>>>(Q, K, V, mask, Out, W);
  }
}